// Round 5
// baseline (2296.906 us; speedup 1.0000x reference)
//
#include <hip/hip_runtime.h>

typedef __attribute__((ext_vector_type(8))) short short8;
typedef __attribute__((ext_vector_type(4))) float f32x4;
typedef __attribute__((ext_vector_type(4))) unsigned short us4v;
typedef unsigned short ushort_t;
typedef unsigned int uint_t;

#define BB 4
#define T_ 1024
#define T2 2048
#define DD 256
#define DIN 512
#define NMARK 64
#define LNEPS 1e-5f
#define KDIV (-0.035977892078032f)

__device__ __forceinline__ ushort_t f2bf(float f) {
  unsigned int u = __float_as_uint(f);
  unsigned int r = (u + 0x7fffu + ((u >> 16) & 1u)) >> 16;
  return (ushort_t)r;
}
__device__ __forceinline__ uint_t pack2(float a, float b) {
  return (uint_t)f2bf(a) | ((uint_t)f2bf(b) << 16);
}
__device__ __forceinline__ uint_t cvtpk(float lo, float hi) {
  uint_t r;
  asm("v_cvt_pk_bf16_f32 %0, %1, %2" : "=v"(r) : "v"(lo), "v"(hi));
  return r;
}

// ---------- init: type/time embeddings -> Xh (bf16), Cur = 0 ----------
__global__ __launch_bounds__(256) void k_init(const float* __restrict__ ev,
                                              const float* __restrict__ tm,
                                              const float* __restrict__ Wt,
                                              const float* __restrict__ bt,
                                              ushort_t* __restrict__ Xh,
                                              float* __restrict__ Cur) {
  const int btq = blockIdx.x;
  const int b = btq >> 10;
  const int t = btq & 1023;
  const int d = threadIdx.x;
  __shared__ float evs[NMARK];
  if (d < NMARK) evs[d] = ev[(size_t)btq * NMARK + d];
  __syncthreads();
  float s = bt[d];
#pragma unroll
  for (int m = 0; m < NMARK; ++m) s += evs[m] * Wt[m * DD + d];
  const float te_type = tanhf(s);
  const float tv = tm[btq];
  const int i = d >> 1;
  const float dv = expf((float)(2 * i) * KDIV);
  const float ang = tv * dv;
  const float te_time = (d & 1) ? cosf(ang) : sinf(ang);
  ushort_t* Xb = Xh + (size_t)b * T2 * DIN;
  const ushort_t tt = f2bf(te_time);
  Xb[(size_t)t * DIN + d] = f2bf(te_type);
  Xb[(size_t)t * DIN + DD + d] = tt;
  Xb[(size_t)(T_ + t) * DIN + d] = 0;
  Xb[(size_t)(T_ + t) * DIN + DD + d] = tt;
  Cur[((size_t)b * T_ + t) * DD + d] = 0.0f;
}

// ---------- weight transpose: W[hl][k][n] f32 -> WT[mat][n][k] bf16 ----------
__global__ __launch_bounds__(256) void k_transW(const float* __restrict__ Wq,
                                                const float* __restrict__ Wk,
                                                const float* __restrict__ Wv,
                                                ushort_t* __restrict__ WT) {
  const int mi = blockIdx.x;
  const int wsel = mi / 12, hl = mi % 12;
  const float* W = ((wsel == 0) ? Wq : (wsel == 1) ? Wk : Wv) + (size_t)hl * DIN * DD;
  const int t = blockIdx.y;
  const int k0 = (t >> 2) * 64, n0 = (t & 3) * 64;
  __shared__ float Ts[64][65];
  const int tid = threadIdx.x;
#pragma unroll
  for (int i = 0; i < 16; ++i) {
    const int idx = tid + i * 256;
    const int r = idx >> 6, c = idx & 63;
    Ts[r][c] = W[(size_t)(k0 + r) * DD + n0 + c];
  }
  __syncthreads();
  ushort_t* D = WT + (size_t)mi * DD * DIN;
#pragma unroll
  for (int i = 0; i < 16; ++i) {
    const int idx = tid + i * 256;
    const int rn = idx >> 6, ck = idx & 63;
    D[(size_t)(n0 + rn) * DIN + k0 + ck] = f2bf(Ts[ck][rn]);
  }
}

// ---------- QKV GEMM: [8192x512]x[512x256] via MFMA; z selects Q/K/V ----------
__global__ __launch_bounds__(256) void k_qkv(const ushort_t* __restrict__ Xh,
                                             const ushort_t* __restrict__ WT,
                                             const float* __restrict__ bq,
                                             const float* __restrict__ bk,
                                             const float* __restrict__ bv,
                                             ushort_t* __restrict__ Qh,
                                             ushort_t* __restrict__ Kh,
                                             ushort_t* __restrict__ VT,
                                             int hl) {
  const int m0 = blockIdx.x * 128;
  const int n0 = blockIdx.y * 128;
  const int wsel = blockIdx.z;
  const ushort_t* Bt = WT + ((size_t)(wsel * 12 + hl)) * DD * DIN + (size_t)n0 * DIN;
  const float* bias = (wsel == 0) ? bq : (wsel == 1) ? bk : bv;

  __shared__ ushort_t As[128 * 64];
  __shared__ ushort_t Bs[128 * 64];
  const int tid = threadIdx.x;
  const int w = tid >> 6, lane = tid & 63;
  const int wr = w >> 1, wc = w & 1;
  const int lr = lane & 15, kg = lane >> 4;

  f32x4 acc[4][4];
  const f32x4 z4 = {0.f, 0.f, 0.f, 0.f};
#pragma unroll
  for (int a = 0; a < 4; ++a)
#pragma unroll
    for (int c = 0; c < 4; ++c) acc[a][c] = z4;

  for (int k0 = 0; k0 < DIN; k0 += 64) {
#pragma unroll
    for (int i = 0; i < 4; ++i) {
      const int idx = tid + i * 256;
      const int row = idx >> 3, ch = idx & 7;
      const int db = row * 128 + ((ch * 16) ^ ((row & 7) << 4));
      uint4 va = *(const uint4*)&Xh[(size_t)(m0 + row) * DIN + k0 + ch * 8];
      *(uint4*)((char*)As + db) = va;
      uint4 vb = *(const uint4*)&Bt[(size_t)row * DIN + k0 + ch * 8];
      *(uint4*)((char*)Bs + db) = vb;
    }
    __syncthreads();
#pragma unroll
    for (int kk = 0; kk < 2; ++kk) {
      short8 af[4], bfr[4];
      const int cb = kk * 64 + kg * 16;
#pragma unroll
      for (int mi = 0; mi < 4; ++mi) {
        const int row = wr * 64 + mi * 16 + lr;
        af[mi] = *(const short8*)((const char*)As + row * 128 + (cb ^ ((row & 7) << 4)));
      }
#pragma unroll
      for (int ni = 0; ni < 4; ++ni) {
        const int row = wc * 64 + ni * 16 + lr;
        bfr[ni] = *(const short8*)((const char*)Bs + row * 128 + (cb ^ ((row & 7) << 4)));
      }
#pragma unroll
      for (int mi = 0; mi < 4; ++mi)
#pragma unroll
        for (int ni = 0; ni < 4; ++ni)
          acc[mi][ni] = __builtin_amdgcn_mfma_f32_16x16x32_bf16(af[mi], bfr[ni], acc[mi][ni], 0, 0, 0);
    }
    __syncthreads();
  }

  if (wsel < 2) {
    ushort_t* C = (wsel == 0) ? Qh : Kh;
#pragma unroll
    for (int mi = 0; mi < 4; ++mi)
#pragma unroll
      for (int ni = 0; ni < 4; ++ni) {
        const int col = n0 + wc * 64 + ni * 16 + lr;
        const float bcol = bias[col];
        const int rbase = m0 + wr * 64 + mi * 16 + kg * 4;
#pragma unroll
        for (int r = 0; r < 4; ++r)
          C[(size_t)(rbase + r) * DD + col] = f2bf(acc[mi][ni][r] + bcol);
      }
  } else {
    const int b = m0 >> 11;
    const int t0 = m0 & 2047;
#pragma unroll
    for (int mi = 0; mi < 4; ++mi)
#pragma unroll
      for (int ni = 0; ni < 4; ++ni) {
        const int col = n0 + wc * 64 + ni * 16 + lr;
        const float bcol = bias[col];
        const int tb = t0 + wr * 64 + mi * 16 + kg * 4;
        uint2 pk;
        pk.x = pack2(acc[mi][ni][0] + bcol, acc[mi][ni][1] + bcol);
        pk.y = pack2(acc[mi][ni][2] + bcol, acc[mi][ni][3] + bcol);
        *(uint2*)(VT + ((size_t)b * DD + col) * T2 + tb) = pk;
      }
  }
}

// ---------- barrier-free flash: one wave owns 16 q-rows end-to-end ----------
// grid 528 x 64 threads. i&7 -> XCD; batch = XCD-pair. k = wave rank (heavy first).
// k<128: flash wave (t0 = 1008-16*(k>>1), k even = bottom half). k>=128: row0 mean.
__global__ __launch_bounds__(64) void k_flash(const ushort_t* __restrict__ Qh,
                                              const ushort_t* __restrict__ Kh,
                                              const ushort_t* __restrict__ VT,
                                              float* __restrict__ Cur,
                                              ushort_t* __restrict__ Xh,
                                              float* __restrict__ out,
                                              const float* __restrict__ nw,
                                              const float* __restrict__ nb,
                                              int lastLayer, int h) {
  const int i = blockIdx.x;
  const int xcd = i & 7;
  const int b = xcd >> 1;
  const int k = ((i >> 3) << 1) | (xcd & 1);
  const int lane = threadIdx.x;

  if (k >= 128) {  // ----- row0: Xh[b,0,0:256] = mean over 2048 V rows -----
    const int col = ((k & 3) << 6) + lane;
    const ushort_t* vp = VT + ((size_t)b * DD + col) * T2;
    float s = 0.f;
    for (int j = 0; j < T2; j += 8) {
      uint4 v = *(const uint4*)(vp + j);
      const uint_t vs[4] = {v.x, v.y, v.z, v.w};
#pragma unroll
      for (int q = 0; q < 4; ++q) {
        s += __uint_as_float(vs[q] << 16);
        s += __uint_as_float(vs[q] & 0xffff0000u);
      }
    }
    Xh[(size_t)b * T2 * DIN + col] = f2bf(s * (1.0f / 2048.0f));
    return;
  }

  const int t0 = 1008 - ((k >> 1) << 4);
  const int half = ((k & 1) == 0) ? 1 : 0;     // even rank = bottom (heavier)
  const int r0 = half ? (T_ + t0) : t0;
  const int nc = ((t0 + 15) >> 6) + 1;          // causal tiles
  const int nt = nc + half;                     // +1 diag tile for bottom
  const int dtile = 16 + (t0 >> 6);
  const int off0 = (T_ + t0) & 63;

  const int kg = lane >> 4, lr = lane & 15;
  const int tmy = t0 + lr;                      // this lane's local t

  // Q B-fragments (col=q=lr), loaded once: qf[kk] covers d = kk*32 + kg*8 .. +7
  short8 qf[8];
  const ushort_t* qb = Qh + ((size_t)b * T2 + r0 + lr) * DD + kg * 8;
#pragma unroll
  for (int kk = 0; kk < 8; ++kk) qf[kk] = *(const short8*)(qb + kk * 32);

  const f32x4 z4 = {0.f, 0.f, 0.f, 0.f};
  f32x4 acc_o[16];                              // O^T[d=db*16+kg*4+r][q=lr]
#pragma unroll
  for (int db = 0; db < 16; ++db) acc_o[db] = z4;
  float m_run = -1e30f, l_run = 0.f;

  for (int kt = 0; kt < nt; ++kt) {
    const int tile = (kt < nc) ? kt : dtile;
    const bool isDiag = (kt >= nc);

    // --- QK^T (swapped): S^T[j = tile*64+jb*16+kg*4+r][q = lr] ---
    f32x4 sa[4];
    const ushort_t* kb = Kh + ((size_t)b * T2 + tile * 64 + lr) * DD + kg * 8;
#pragma unroll
    for (int jb = 0; jb < 4; ++jb) {
      sa[jb] = z4;
#pragma unroll
      for (int kk = 0; kk < 8; ++kk) {
        short8 kf = *(const short8*)(kb + jb * 16 * DD + kk * 32);
        sa[jb] = __builtin_amdgcn_mfma_f32_16x16x32_bf16(kf, qf[kk], sa[jb], 0, 0, 0);
      }
    }

    // --- mask + scale + online softmax (wave-local) ---
    float p[16];
    float tmax = -1e30f;
#pragma unroll
    for (int jb = 0; jb < 4; ++jb)
#pragma unroll
      for (int r = 0; r < 4; ++r) {
        const int jl = jb * 16 + kg * 4 + r;
        const bool valid = isDiag ? (jl == off0 + lr) : ((tile * 64 + jl) < tmy);
        const float sv = valid ? sa[jb][r] * 0.0625f : -1e30f;
        p[jb * 4 + r] = sv;
        tmax = fmaxf(tmax, sv);
      }
    tmax = fmaxf(tmax, __shfl_xor(tmax, 16, 64));
    tmax = fmaxf(tmax, __shfl_xor(tmax, 32, 64));
    const float m_new = fmaxf(m_run, tmax);
    const float fac = __expf(m_run - m_new);
    float psum = 0.f;
#pragma unroll
    for (int e = 0; e < 16; ++e) {
      const float pe = (p[e] > -1e29f) ? __expf(p[e] - m_new) : 0.0f;
      p[e] = pe;
      psum += pe;
    }
    psum += __shfl_xor(psum, 16, 64);
    psum += __shfl_xor(psum, 32, 64);
    l_run = l_run * fac + psum;
    m_run = m_new;

    // --- rescale O (scalar per lane) ---
#pragma unroll
    for (int db = 0; db < 16; ++db) acc_o[db] *= fac;

    // --- pack P into B-fragments (pure lane-local; k-slot sigma mapping) ---
    uint_t pk00 = cvtpk(p[0], p[1]),  pk01 = cvtpk(p[2], p[3]);
    uint_t pk10 = cvtpk(p[4], p[5]),  pk11 = cvtpk(p[6], p[7]);
    uint_t pk20 = cvtpk(p[8], p[9]),  pk21 = cvtpk(p[10], p[11]);
    uint_t pk30 = cvtpk(p[12], p[13]), pk31 = cvtpk(p[14], p[15]);
    union U8 { uint4 u; short8 s; };
    U8 pf0, pf1;
    pf0.u.x = pk00; pf0.u.y = pk01; pf0.u.z = pk10; pf0.u.w = pk11;
    pf1.u.x = pk20; pf1.u.y = pk21; pf1.u.z = pk30; pf1.u.w = pk31;

    // --- PV: O^T += V^T * P^T; V A-frag slot (kg,e) <- j = jb2*32+(e>>2)*16+kg*4+(e&3)
    const ushort_t* vb = VT + ((size_t)b * DD + lr) * T2 + tile * 64 + kg * 4;
#pragma unroll
    for (int db = 0; db < 16; ++db) {
      const ushort_t* vr = vb + (size_t)db * 16 * T2;
      uint2 vlo0 = *(const uint2*)(vr);
      uint2 vhi0 = *(const uint2*)(vr + 16);
      uint2 vlo1 = *(const uint2*)(vr + 32);
      uint2 vhi1 = *(const uint2*)(vr + 48);
      U8 vf0, vf1;
      vf0.u.x = vlo0.x; vf0.u.y = vlo0.y; vf0.u.z = vhi0.x; vf0.u.w = vhi0.y;
      vf1.u.x = vlo1.x; vf1.u.y = vlo1.y; vf1.u.z = vhi1.x; vf1.u.w = vhi1.y;
      acc_o[db] = __builtin_amdgcn_mfma_f32_16x16x32_bf16(vf0.s, pf0.s, acc_o[db], 0, 0, 0);
      acc_o[db] = __builtin_amdgcn_mfma_f32_16x16x32_bf16(vf1.s, pf1.s, acc_o[db], 0, 0, 0);
    }
  }

  // ---------- epilogue (wave-local) ----------
  const float oinv = 1.0f / l_run;   // top row 0: l=0 -> inf, store skipped
  const int t = t0 + lr;

  if (!half) {
    if (t != 0) {
      ushort_t* xp = Xh + ((size_t)b * T2 + t) * DIN + kg * 4;
#pragma unroll
      for (int db = 0; db < 16; ++db) {
        us4v o;
#pragma unroll
        for (int r = 0; r < 4; ++r) o[r] = f2bf(acc_o[db][r] * oinv);
        *(us4v*)(xp + db * 16) = o;
      }
    }
  } else {
    float* cp = Cur + ((size_t)b * T_ + t) * DD + kg * 4;
    float s1 = 0.f, s2 = 0.f;
#pragma unroll
    for (int db = 0; db < 16; ++db) {
      f32x4 c4 = *(const f32x4*)(cp + db * 16);
#pragma unroll
      for (int r = 0; r < 4; ++r) {
        const float x = tanhf(acc_o[db][r] * oinv) + c4[r];
        acc_o[db][r] = x;
        s1 += x;
        s2 += x * x;
      }
    }
    s1 += __shfl_xor(s1, 16, 64); s1 += __shfl_xor(s1, 32, 64);
    s2 += __shfl_xor(s2, 16, 64); s2 += __shfl_xor(s2, 32, 64);
    const float mean = s1 * (1.0f / 256.0f);
    const float var = s2 * (1.0f / 256.0f) - mean * mean;
    const float rinv = rsqrtf(var + LNEPS);
    ushort_t* xp = Xh + ((size_t)b * T2 + T_ + t) * DIN + kg * 4;
    if (lastLayer) {
      float* op = out + ((size_t)b * T_ + t) * (DD * 4) + h * DD + kg * 4;
      const us4v zz = {0, 0, 0, 0};
#pragma unroll
      for (int db = 0; db < 16; ++db) {
        f32x4 w4 = *(const f32x4*)&nw[db * 16 + kg * 4];
        f32x4 b4 = *(const f32x4*)&nb[db * 16 + kg * 4];
        f32x4 y;
#pragma unroll
        for (int r = 0; r < 4; ++r) y[r] = (acc_o[db][r] - mean) * rinv * w4[r] + b4[r];
        *(f32x4*)(op + db * 16) = y;
        *(f32x4*)(cp + db * 16) = z4;
        *(us4v*)(xp + db * 16) = zz;
      }
    } else {
#pragma unroll
      for (int db = 0; db < 16; ++db) {
        f32x4 w4 = *(const f32x4*)&nw[db * 16 + kg * 4];
        f32x4 b4 = *(const f32x4*)&nb[db * 16 + kg * 4];
        f32x4 y;
        us4v yh;
#pragma unroll
        for (int r = 0; r < 4; ++r) {
          y[r] = (acc_o[db][r] - mean) * rinv * w4[r] + b4[r];
          yh[r] = f2bf(y[r]);
        }
        *(f32x4*)(cp + db * 16) = y;
        *(us4v*)(xp + db * 16) = yh;
      }
    }
  }
}

extern "C" void kernel_launch(void* const* d_in, const int* in_sizes, int n_in,
                              void* d_out, int out_size, void* d_ws, size_t ws_size,
                              hipStream_t stream) {
  const float* ev = (const float*)d_in[0];
  const float* tm = (const float*)d_in[1];
  const float* Wt = (const float*)d_in[3];
  const float* bt = (const float*)d_in[4];
  const float* Wq = (const float*)d_in[5];
  const float* bq = (const float*)d_in[6];
  const float* Wk = (const float*)d_in[7];
  const float* bk = (const float*)d_in[8];
  const float* Wv = (const float*)d_in[9];
  const float* bv = (const float*)d_in[10];
  const float* nw = (const float*)d_in[11];
  const float* nb = (const float*)d_in[12];
  float* out = (float*)d_out;

  char* p = (char*)d_ws;
  ushort_t* Xh = (ushort_t*)p; p += (size_t)BB * T2 * DIN * 2;   // 8.39 MB
  ushort_t* Qh = (ushort_t*)p; p += (size_t)BB * T2 * DD * 2;    // 4.19 MB
  ushort_t* Kh = (ushort_t*)p; p += (size_t)BB * T2 * DD * 2;
  ushort_t* VT = (ushort_t*)p; p += (size_t)BB * T2 * DD * 2;
  float* Cur   = (float*)p;    p += (size_t)BB * T_ * DD * 4;    // 4.19 MB
  ushort_t* WT = (ushort_t*)p;                                   // 9.44 MB

  k_init<<<BB * T_, 256, 0, stream>>>(ev, tm, Wt, bt, Xh, Cur);
  k_transW<<<dim3(36, 32), 256, 0, stream>>>(Wq, Wk, Wv, WT);

  for (int h = 0; h < 4; ++h) {
    for (int l = 0; l < 3; ++l) {
      const int hl = h * 3 + l;
      const size_t boff = (size_t)hl * DD;
      k_qkv<<<dim3(64, 2, 3), 256, 0, stream>>>(Xh, WT, bq + boff, bk + boff, bv + boff,
                                                Qh, Kh, VT, hl);
      k_flash<<<528, 64, 0, stream>>>(Qh, Kh, VT, Cur, Xh, out, nw, nb,
                                      (l == 2) ? 1 : 0, h);
    }
  }
}

// Round 6
// 2079.601 us; speedup vs baseline: 1.1045x; 1.1045x over previous
//
#include <hip/hip_runtime.h>

typedef __attribute__((ext_vector_type(8))) short short8;
typedef __attribute__((ext_vector_type(4))) float f32x4;
typedef __attribute__((ext_vector_type(4))) unsigned short us4v;
typedef unsigned short ushort_t;
typedef unsigned int uint_t;

#define BB 4
#define T_ 1024
#define T2 2048
#define DD 256
#define DIN 512
#define NMARK 64
#define LNEPS 1e-5f
#define KDIV (-0.035977892078032f)

__device__ __forceinline__ ushort_t f2bf(float f) {
  unsigned int u = __float_as_uint(f);
  unsigned int r = (u + 0x7fffu + ((u >> 16) & 1u)) >> 16;
  return (ushort_t)r;
}
__device__ __forceinline__ uint_t pack2(float a, float b) {
  return (uint_t)f2bf(a) | ((uint_t)f2bf(b) << 16);
}
__device__ __forceinline__ uint_t cvtpk(float lo, float hi) {
  uint_t r;
  asm("v_cvt_pk_bf16_f32 %0, %1, %2" : "=v"(r) : "v"(lo), "v"(hi));
  return r;
}

// ---------- init: type/time embeddings -> Xh (bf16), Cur = 0 ----------
__global__ __launch_bounds__(256) void k_init(const float* __restrict__ ev,
                                              const float* __restrict__ tm,
                                              const float* __restrict__ Wt,
                                              const float* __restrict__ bt,
                                              ushort_t* __restrict__ Xh,
                                              float* __restrict__ Cur) {
  const int btq = blockIdx.x;
  const int b = btq >> 10;
  const int t = btq & 1023;
  const int d = threadIdx.x;
  __shared__ float evs[NMARK];
  if (d < NMARK) evs[d] = ev[(size_t)btq * NMARK + d];
  __syncthreads();
  float s = bt[d];
#pragma unroll
  for (int m = 0; m < NMARK; ++m) s += evs[m] * Wt[m * DD + d];
  const float te_type = tanhf(s);
  const float tv = tm[btq];
  const int i = d >> 1;
  const float dv = expf((float)(2 * i) * KDIV);
  const float ang = tv * dv;
  const float te_time = (d & 1) ? cosf(ang) : sinf(ang);
  ushort_t* Xb = Xh + (size_t)b * T2 * DIN;
  const ushort_t tt = f2bf(te_time);
  Xb[(size_t)t * DIN + d] = f2bf(te_type);
  Xb[(size_t)t * DIN + DD + d] = tt;
  Xb[(size_t)(T_ + t) * DIN + d] = 0;
  Xb[(size_t)(T_ + t) * DIN + DD + d] = tt;
  Cur[((size_t)b * T_ + t) * DD + d] = 0.0f;
}

// ---------- weight transpose: W[hl][k][n] f32 -> WT[mat][n][k] bf16 ----------
__global__ __launch_bounds__(256) void k_transW(const float* __restrict__ Wq,
                                                const float* __restrict__ Wk,
                                                const float* __restrict__ Wv,
                                                ushort_t* __restrict__ WT) {
  const int mi = blockIdx.x;
  const int wsel = mi / 12, hl = mi % 12;
  const float* W = ((wsel == 0) ? Wq : (wsel == 1) ? Wk : Wv) + (size_t)hl * DIN * DD;
  const int t = blockIdx.y;
  const int k0 = (t >> 2) * 64, n0 = (t & 3) * 64;
  __shared__ float Ts[64][65];
  const int tid = threadIdx.x;
#pragma unroll
  for (int i = 0; i < 16; ++i) {
    const int idx = tid + i * 256;
    const int r = idx >> 6, c = idx & 63;
    Ts[r][c] = W[(size_t)(k0 + r) * DD + n0 + c];
  }
  __syncthreads();
  ushort_t* D = WT + (size_t)mi * DD * DIN;
#pragma unroll
  for (int i = 0; i < 16; ++i) {
    const int idx = tid + i * 256;
    const int rn = idx >> 6, ck = idx & 63;
    D[(size_t)(n0 + rn) * DIN + k0 + ck] = f2bf(Ts[ck][rn]);
  }
}

// ---------- QKV GEMM: [8192x512]x[512x256] via MFMA; z selects Q/K/V ----------
__global__ __launch_bounds__(256) void k_qkv(const ushort_t* __restrict__ Xh,
                                             const ushort_t* __restrict__ WT,
                                             const float* __restrict__ bq,
                                             const float* __restrict__ bk,
                                             const float* __restrict__ bv,
                                             ushort_t* __restrict__ Qh,
                                             ushort_t* __restrict__ Kh,
                                             ushort_t* __restrict__ VT,
                                             int hl) {
  const int m0 = blockIdx.x * 128;
  const int n0 = blockIdx.y * 128;
  const int wsel = blockIdx.z;
  const ushort_t* Bt = WT + ((size_t)(wsel * 12 + hl)) * DD * DIN + (size_t)n0 * DIN;
  const float* bias = (wsel == 0) ? bq : (wsel == 1) ? bk : bv;

  __shared__ ushort_t As[128 * 64];
  __shared__ ushort_t Bs[128 * 64];
  const int tid = threadIdx.x;
  const int w = tid >> 6, lane = tid & 63;
  const int wr = w >> 1, wc = w & 1;
  const int lr = lane & 15, kg = lane >> 4;

  f32x4 acc[4][4];
  const f32x4 z4 = {0.f, 0.f, 0.f, 0.f};
#pragma unroll
  for (int a = 0; a < 4; ++a)
#pragma unroll
    for (int c = 0; c < 4; ++c) acc[a][c] = z4;

  for (int k0 = 0; k0 < DIN; k0 += 64) {
#pragma unroll
    for (int i = 0; i < 4; ++i) {
      const int idx = tid + i * 256;
      const int row = idx >> 3, ch = idx & 7;
      const int db = row * 128 + ((ch * 16) ^ ((row & 7) << 4));
      uint4 va = *(const uint4*)&Xh[(size_t)(m0 + row) * DIN + k0 + ch * 8];
      *(uint4*)((char*)As + db) = va;
      uint4 vb = *(const uint4*)&Bt[(size_t)row * DIN + k0 + ch * 8];
      *(uint4*)((char*)Bs + db) = vb;
    }
    __syncthreads();
#pragma unroll
    for (int kk = 0; kk < 2; ++kk) {
      short8 af[4], bfr[4];
      const int cb = kk * 64 + kg * 16;
#pragma unroll
      for (int mi = 0; mi < 4; ++mi) {
        const int row = wr * 64 + mi * 16 + lr;
        af[mi] = *(const short8*)((const char*)As + row * 128 + (cb ^ ((row & 7) << 4)));
      }
#pragma unroll
      for (int ni = 0; ni < 4; ++ni) {
        const int row = wc * 64 + ni * 16 + lr;
        bfr[ni] = *(const short8*)((const char*)Bs + row * 128 + (cb ^ ((row & 7) << 4)));
      }
#pragma unroll
      for (int mi = 0; mi < 4; ++mi)
#pragma unroll
        for (int ni = 0; ni < 4; ++ni)
          acc[mi][ni] = __builtin_amdgcn_mfma_f32_16x16x32_bf16(af[mi], bfr[ni], acc[mi][ni], 0, 0, 0);
    }
    __syncthreads();
  }

  if (wsel < 2) {
    ushort_t* C = (wsel == 0) ? Qh : Kh;
#pragma unroll
    for (int mi = 0; mi < 4; ++mi)
#pragma unroll
      for (int ni = 0; ni < 4; ++ni) {
        const int col = n0 + wc * 64 + ni * 16 + lr;
        const float bcol = bias[col];
        const int rbase = m0 + wr * 64 + mi * 16 + kg * 4;
#pragma unroll
        for (int r = 0; r < 4; ++r)
          C[(size_t)(rbase + r) * DD + col] = f2bf(acc[mi][ni][r] + bcol);
      }
  } else {
    const int b = m0 >> 11;
    const int t0 = m0 & 2047;
#pragma unroll
    for (int mi = 0; mi < 4; ++mi)
#pragma unroll
      for (int ni = 0; ni < 4; ++ni) {
        const int col = n0 + wc * 64 + ni * 16 + lr;
        const float bcol = bias[col];
        const int tb = t0 + wr * 64 + mi * 16 + kg * 4;
        uint2 pk;
        pk.x = pack2(acc[mi][ni][0] + bcol, acc[mi][ni][1] + bcol);
        pk.y = pack2(acc[mi][ni][2] + bcol, acc[mi][ni][3] + bcol);
        *(uint2*)(VT + ((size_t)b * DD + col) * T2 + tb) = pk;
      }
  }
}

// ---------- flash: 4 waves = 2 q-groups x 2 tile-parities over 32 q-rows ----------
// grid 260 x 256. blocks 0..3: row0 mean-V. blocks 4..259: flash, heavy-first.
// LDS: Ks [64 rows][512B] swz | Vs [256 d][128B] swz; end: reuse for O-merge.
__global__ __launch_bounds__(256) void k_flash(const ushort_t* __restrict__ Qh,
                                               const ushort_t* __restrict__ Kh,
                                               const ushort_t* __restrict__ VT,
                                               float* __restrict__ Cur,
                                               ushort_t* __restrict__ Xh,
                                               float* __restrict__ out,
                                               const float* __restrict__ nw,
                                               const float* __restrict__ nb,
                                               int lastLayer, int h) {
  __shared__ char lds[65536];
  const int tid = threadIdx.x;
  const int bx = blockIdx.x;

  if (bx < 4) {  // ----- row0: Xh[b,0,0:256] = mean over all 2048 V rows -----
    const int b = bx;
    const ushort_t* vp = VT + ((size_t)b * DD + tid) * T2;
    float s = 0.f;
#pragma unroll 4
    for (int j = 0; j < T2; j += 8) {
      uint4 v = *(const uint4*)(vp + j);
      const uint_t vs[4] = {v.x, v.y, v.z, v.w};
#pragma unroll
      for (int q = 0; q < 4; ++q) {
        s += __uint_as_float(vs[q] << 16);
        s += __uint_as_float(vs[q] & 0xffff0000u);
      }
    }
    Xh[(size_t)b * T2 * DIN + tid] = f2bf(s * (1.0f / 2048.0f));
    return;
  }

  char* Ks = lds;
  char* Vs = lds + 32768;

  const int c = bx - 4;
  const int b = c & 3;
  const int cc = c >> 2;                  // 0..63
  const int tcq = 31 - (cc >> 1);         // 32-row chunk, heavy first
  const int half = ((cc & 1) == 0) ? 1 : 0;
  const int t0 = tcq * 32;
  const int ntop = (tcq >> 1) + 1;
  const int nt = ntop + half;
  const int dtile = 16 + (tcq >> 1);
  const int off0 = (tcq & 1) * 32;        // diag row offset within dtile

  const int w = tid >> 6, lane = tid & 63;
  const int kg = lane >> 4, lr = lane & 15;
  const int qg = w & 1;                    // q-group (16 rows)
  const int par = w >> 1;                  // tile parity this wave computes
  const int tloc = qg * 16 + lr;
  const int t = t0 + tloc;                 // lane's t for masking
  const int r0lane = (half ? T_ : 0) + t;  // global Q row

  // Q B-frags, once: qf[kk] = Q[r0lane][kk*32 + kg*8 .. +7]
  short8 qf[8];
  {
    const ushort_t* qb = Qh + ((size_t)b * T2 + r0lane) * DD + kg * 8;
#pragma unroll
    for (int kk = 0; kk < 8; ++kk) qf[kk] = *(const short8*)(qb + kk * 32);
  }

  const f32x4 z4 = {0.f, 0.f, 0.f, 0.f};
  f32x4 acc_o[16];                         // O^T[d=db*16+kg*4+r][q=lr]
#pragma unroll
  for (int db = 0; db < 16; ++db) acc_o[db] = z4;
  float m_run = -1e30f, l_run = 0.f;

  uint4 kreg[8], vreg[8];
#define LOADT(TILE)                                                                  \
  {                                                                                  \
    const int _tt = (TILE);                                                          \
    _Pragma("unroll") for (int s = 0; s < 8; ++s) {                                  \
      const int idx = tid + s * 256;                                                 \
      const int j = idx >> 5, ch = idx & 31;                                         \
      kreg[s] = *(const uint4*)&Kh[((size_t)b * T2 + _tt * 64 + j) * DD + ch * 8];   \
      const int d = idx >> 3, tc = idx & 7;                                          \
      vreg[s] = *(const uint4*)&VT[((size_t)b * DD + d) * T2 + _tt * 64 + tc * 8];   \
    }                                                                                \
  }

  LOADT(0);

  for (int kt = 0; kt < nt; ++kt) {
    const int tile = (kt < ntop) ? kt : dtile;
    const bool isDiag = (kt >= ntop);

    __syncthreads();  // all waves done reading prev tile
#pragma unroll
    for (int s = 0; s < 8; ++s) {
      const int idx = tid + s * 256;
      const int j = idx >> 5, ch = idx & 31;
      *(uint4*)(Ks + j * 512 + ((ch * 16) ^ ((j & 7) << 4))) = kreg[s];
      const int d = idx >> 3, tc = idx & 7;
      *(uint4*)(Vs + d * 128 + ((tc * 16) ^ ((d & 7) << 4))) = vreg[s];
    }
    __syncthreads();
    if (kt + 1 < nt) LOADT((kt + 1 < ntop) ? (kt + 1) : dtile);

    if ((kt & 1) == par) {
      // --- QK^T (swapped): S^T[j = tile*64+jb*16+kg*4+r][q = lr] ---
      f32x4 sa[4];
#pragma unroll
      for (int jb = 0; jb < 4; ++jb) {
        sa[jb] = z4;
        const int rowj = jb * 16 + lr;
        const int base = rowj * 512;
        const int swj = (rowj & 7) << 4;
#pragma unroll
        for (int kk = 0; kk < 8; ++kk) {
          short8 kf = *(const short8*)(Ks + base + ((kk * 64 + kg * 16) ^ swj));
          sa[jb] = __builtin_amdgcn_mfma_f32_16x16x32_bf16(kf, qf[kk], sa[jb], 0, 0, 0);
        }
      }
      // --- mask + scale + online softmax (wave-local) ---
      float p[16];
      float tmax = -1e30f;
#pragma unroll
      for (int jb = 0; jb < 4; ++jb)
#pragma unroll
        for (int r = 0; r < 4; ++r) {
          const int jl = jb * 16 + kg * 4 + r;
          const bool valid = isDiag ? (jl == off0 + tloc) : ((tile * 64 + jl) < t);
          const float sv = valid ? sa[jb][r] * 0.0625f : -1e30f;
          p[jb * 4 + r] = sv;
          tmax = fmaxf(tmax, sv);
        }
      tmax = fmaxf(tmax, __shfl_xor(tmax, 16, 64));
      tmax = fmaxf(tmax, __shfl_xor(tmax, 32, 64));
      const float m_new = fmaxf(m_run, tmax);
      const float fac = __expf(m_run - m_new);
      float psum = 0.f;
#pragma unroll
      for (int e = 0; e < 16; ++e) {
        const float pe = (p[e] > -1e29f) ? __expf(p[e] - m_new) : 0.0f;
        p[e] = pe;
        psum += pe;
      }
      psum += __shfl_xor(psum, 16, 64);
      psum += __shfl_xor(psum, 32, 64);
      l_run = l_run * fac + psum;
      m_run = m_new;
#pragma unroll
      for (int db = 0; db < 16; ++db) acc_o[db] *= fac;

      // --- pack P into B-frags (lane-local; sigma k-slot mapping) ---
      union U8 { uint4 u; short8 s; };
      U8 pf0, pf1;
      pf0.u.x = cvtpk(p[0], p[1]);   pf0.u.y = cvtpk(p[2], p[3]);
      pf0.u.z = cvtpk(p[4], p[5]);   pf0.u.w = cvtpk(p[6], p[7]);
      pf1.u.x = cvtpk(p[8], p[9]);   pf1.u.y = cvtpk(p[10], p[11]);
      pf1.u.z = cvtpk(p[12], p[13]); pf1.u.w = cvtpk(p[14], p[15]);

      // --- PV from LDS: O^T += V^T * P^T ---
#pragma unroll
      for (int db = 0; db < 16; ++db) {
        const int d = db * 16 + lr;
        const char* vb = Vs + d * 128;
        const int swd = (d & 7) << 4;
        uint2 a0 = *(const uint2*)(vb + ((kg * 8) ^ swd));
        uint2 a1 = *(const uint2*)(vb + ((32 + kg * 8) ^ swd));
        uint2 a2 = *(const uint2*)(vb + ((64 + kg * 8) ^ swd));
        uint2 a3 = *(const uint2*)(vb + ((96 + kg * 8) ^ swd));
        U8 vf0, vf1;
        vf0.u.x = a0.x; vf0.u.y = a0.y; vf0.u.z = a1.x; vf0.u.w = a1.y;
        vf1.u.x = a2.x; vf1.u.y = a2.y; vf1.u.z = a3.x; vf1.u.w = a3.y;
        acc_o[db] = __builtin_amdgcn_mfma_f32_16x16x32_bf16(vf0.s, pf0.s, acc_o[db], 0, 0, 0);
        acc_o[db] = __builtin_amdgcn_mfma_f32_16x16x32_bf16(vf1.s, pf1.s, acc_o[db], 0, 0, 0);
      }
    }
  }

  // ---------- merge parity pairs (waves w and w^2 share q-rows) ----------
  __syncthreads();
  float* Osx = (float*)lds;                 // [2][256][17] f32 = 34816 B
  float* mArr = (float*)(lds + 35840);      // [4][16]
  float* lArr = mArr + 64;
  if (kg == 0) { mArr[w * 16 + lr] = m_run; lArr[w * 16 + lr] = l_run; }
  __syncthreads();
  const int pw = w ^ 2;
  const float m_p = mArr[pw * 16 + lr];
  const float l_p = lArr[pw * 16 + lr];
  const float m_star = fmaxf(m_run, m_p);
  const float fs = __expf(m_run - m_star);
  const float fp = __expf(m_p - m_star);
  const float l_star = l_run * fs + l_p * fp;
  float* myOs = Osx + qg * (256 * 17);
  if (w >= 2) {
#pragma unroll
    for (int db = 0; db < 16; ++db)
#pragma unroll
      for (int r = 0; r < 4; ++r)
        myOs[(db * 16 + kg * 4 + r) * 17 + lr] = acc_o[db][r] * fs;
  }
  __syncthreads();
  if (w >= 2) return;
#pragma unroll
  for (int db = 0; db < 16; ++db)
#pragma unroll
    for (int r = 0; r < 4; ++r)
      acc_o[db][r] = acc_o[db][r] * fs + myOs[(db * 16 + kg * 4 + r) * 17 + lr];

  const float oinv = 1.0f / l_star;   // t==0 (top): l_star==0 -> store skipped

  // ---------- epilogue (wave-local; waves 0,1 only) ----------
  if (!half) {
    if (t != 0) {
      ushort_t* xp = Xh + ((size_t)b * T2 + t) * DIN + kg * 4;
#pragma unroll
      for (int db = 0; db < 16; ++db) {
        us4v o;
#pragma unroll
        for (int r = 0; r < 4; ++r) o[r] = f2bf(acc_o[db][r] * oinv);
        *(us4v*)(xp + db * 16) = o;
      }
    }
  } else {
    float* cp = Cur + ((size_t)b * T_ + t) * DD + kg * 4;
    float s1 = 0.f, s2 = 0.f;
#pragma unroll
    for (int db = 0; db < 16; ++db) {
      f32x4 c4 = *(const f32x4*)(cp + db * 16);
#pragma unroll
      for (int r = 0; r < 4; ++r) {
        const float x = tanhf(acc_o[db][r] * oinv) + c4[r];
        acc_o[db][r] = x;
        s1 += x;
        s2 += x * x;
      }
    }
    s1 += __shfl_xor(s1, 16, 64); s1 += __shfl_xor(s1, 32, 64);
    s2 += __shfl_xor(s2, 16, 64); s2 += __shfl_xor(s2, 32, 64);
    const float mean = s1 * (1.0f / 256.0f);
    const float var = s2 * (1.0f / 256.0f) - mean * mean;
    const float rinv = rsqrtf(var + LNEPS);
    ushort_t* xp = Xh + ((size_t)b * T2 + T_ + t) * DIN + kg * 4;
    if (lastLayer) {
      float* op = out + ((size_t)b * T_ + t) * (DD * 4) + h * DD + kg * 4;
      const us4v zz = {0, 0, 0, 0};
      const f32x4 zf = {0.f, 0.f, 0.f, 0.f};
#pragma unroll
      for (int db = 0; db < 16; ++db) {
        f32x4 w4 = *(const f32x4*)&nw[db * 16 + kg * 4];
        f32x4 b4 = *(const f32x4*)&nb[db * 16 + kg * 4];
        f32x4 y;
#pragma unroll
        for (int r = 0; r < 4; ++r) y[r] = (acc_o[db][r] - mean) * rinv * w4[r] + b4[r];
        *(f32x4*)(op + db * 16) = y;
        *(f32x4*)(cp + db * 16) = zf;
        *(us4v*)(xp + db * 16) = zz;
      }
    } else {
#pragma unroll
      for (int db = 0; db < 16; ++db) {
        f32x4 w4 = *(const f32x4*)&nw[db * 16 + kg * 4];
        f32x4 b4 = *(const f32x4*)&nb[db * 16 + kg * 4];
        f32x4 y;
        us4v yh;
#pragma unroll
        for (int r = 0; r < 4; ++r) {
          y[r] = (acc_o[db][r] - mean) * rinv * w4[r] + b4[r];
          yh[r] = f2bf(y[r]);
        }
        *(f32x4*)(cp + db * 16) = y;
        *(us4v*)(xp + db * 16) = yh;
      }
    }
  }
}

extern "C" void kernel_launch(void* const* d_in, const int* in_sizes, int n_in,
                              void* d_out, int out_size, void* d_ws, size_t ws_size,
                              hipStream_t stream) {
  const float* ev = (const float*)d_in[0];
  const float* tm = (const float*)d_in[1];
  const float* Wt = (const float*)d_in[3];
  const float* bt = (const float*)d_in[4];
  const float* Wq = (const float*)d_in[5];
  const float* bq = (const float*)d_in[6];
  const float* Wk = (const float*)d_in[7];
  const float* bk = (const float*)d_in[8];
  const float* Wv = (const float*)d_in[9];
  const float* bv = (const float*)d_in[10];
  const float* nw = (const float*)d_in[11];
  const float* nb = (const float*)d_in[12];
  float* out = (float*)d_out;

  char* p = (char*)d_ws;
  ushort_t* Xh = (ushort_t*)p; p += (size_t)BB * T2 * DIN * 2;   // 8.39 MB
  ushort_t* Qh = (ushort_t*)p; p += (size_t)BB * T2 * DD * 2;    // 4.19 MB
  ushort_t* Kh = (ushort_t*)p; p += (size_t)BB * T2 * DD * 2;
  ushort_t* VT = (ushort_t*)p; p += (size_t)BB * T2 * DD * 2;
  float* Cur   = (float*)p;    p += (size_t)BB * T_ * DD * 4;    // 4.19 MB
  ushort_t* WT = (ushort_t*)p;                                   // 9.44 MB

  k_init<<<BB * T_, 256, 0, stream>>>(ev, tm, Wt, bt, Xh, Cur);
  k_transW<<<dim3(36, 32), 256, 0, stream>>>(Wq, Wk, Wv, WT);

  for (int h = 0; h < 4; ++h) {
    for (int l = 0; l < 3; ++l) {
      const int hl = h * 3 + l;
      const size_t boff = (size_t)hl * DD;
      k_qkv<<<dim3(64, 2, 3), 256, 0, stream>>>(Xh, WT, bq + boff, bk + boff, bv + boff,
                                                Qh, Kh, VT, hl);
      k_flash<<<260, 256, 0, stream>>>(Qh, Kh, VT, Cur, Xh, out, nw, nb,
                                       (l == 2) ? 1 : 0, h);
    }
  }
}

// Round 7
// 933.845 us; speedup vs baseline: 2.4596x; 2.2269x over previous
//
#include <hip/hip_runtime.h>

typedef __attribute__((ext_vector_type(8))) short short8;
typedef __attribute__((ext_vector_type(4))) float f32x4;
typedef __attribute__((ext_vector_type(4))) unsigned short us4v;
typedef unsigned short ushort_t;
typedef unsigned int uint_t;

#define BB 4
#define T_ 1024
#define T2 2048
#define DD 256
#define DIN 512
#define NMARK 64
#define LNEPS 1e-5f
#define KDIV (-0.035977892078032f)

__device__ __forceinline__ ushort_t f2bf(float f) {
  unsigned int u = __float_as_uint(f);
  unsigned int r = (u + 0x7fffu + ((u >> 16) & 1u)) >> 16;
  return (ushort_t)r;
}
__device__ __forceinline__ uint_t pack2(float a, float b) {
  return (uint_t)f2bf(a) | ((uint_t)f2bf(b) << 16);
}
__device__ __forceinline__ uint_t cvtpk(float lo, float hi) {
  uint_t r;
  asm("v_cvt_pk_bf16_f32 %0, %1, %2" : "=v"(r) : "v"(lo), "v"(hi));
  return r;
}

typedef const __attribute__((address_space(1))) unsigned int* as1cu32;
typedef __attribute__((address_space(3))) unsigned int* as3u32;
__device__ __forceinline__ void async_copy16(const void* g, void* l) {
  __builtin_amdgcn_global_load_lds((as1cu32)g, (as3u32)l, 16, 0, 0);
}

// ---------- init: type/time embeddings -> Xh (bf16), Cur = 0 ----------
__global__ __launch_bounds__(256) void k_init(const float* __restrict__ ev,
                                              const float* __restrict__ tm,
                                              const float* __restrict__ Wt,
                                              const float* __restrict__ bt,
                                              ushort_t* __restrict__ Xh,
                                              float* __restrict__ Cur) {
  const int btq = blockIdx.x;
  const int b = btq >> 10;
  const int t = btq & 1023;
  const int d = threadIdx.x;
  __shared__ float evs[NMARK];
  if (d < NMARK) evs[d] = ev[(size_t)btq * NMARK + d];
  __syncthreads();
  float s = bt[d];
#pragma unroll
  for (int m = 0; m < NMARK; ++m) s += evs[m] * Wt[m * DD + d];
  const float te_type = tanhf(s);
  const float tv = tm[btq];
  const int i = d >> 1;
  const float dv = expf((float)(2 * i) * KDIV);
  const float ang = tv * dv;
  const float te_time = (d & 1) ? cosf(ang) : sinf(ang);
  ushort_t* Xb = Xh + (size_t)b * T2 * DIN;
  const ushort_t tt = f2bf(te_time);
  Xb[(size_t)t * DIN + d] = f2bf(te_type);
  Xb[(size_t)t * DIN + DD + d] = tt;
  Xb[(size_t)(T_ + t) * DIN + d] = 0;
  Xb[(size_t)(T_ + t) * DIN + DD + d] = tt;
  Cur[((size_t)b * T_ + t) * DD + d] = 0.0f;
}

// ---------- weight transpose: W[hl][k][n] f32 -> WT[mat][n][k] bf16 ----------
__global__ __launch_bounds__(256) void k_transW(const float* __restrict__ Wq,
                                                const float* __restrict__ Wk,
                                                const float* __restrict__ Wv,
                                                ushort_t* __restrict__ WT) {
  const int mi = blockIdx.x;
  const int wsel = mi / 12, hl = mi % 12;
  const float* W = ((wsel == 0) ? Wq : (wsel == 1) ? Wk : Wv) + (size_t)hl * DIN * DD;
  const int t = blockIdx.y;
  const int k0 = (t >> 2) * 64, n0 = (t & 3) * 64;
  __shared__ float Ts[64][65];
  const int tid = threadIdx.x;
#pragma unroll
  for (int i = 0; i < 16; ++i) {
    const int idx = tid + i * 256;
    const int r = idx >> 6, c = idx & 63;
    Ts[r][c] = W[(size_t)(k0 + r) * DD + n0 + c];
  }
  __syncthreads();
  ushort_t* D = WT + (size_t)mi * DD * DIN;
#pragma unroll
  for (int i = 0; i < 16; ++i) {
    const int idx = tid + i * 256;
    const int rn = idx >> 6, ck = idx & 63;
    D[(size_t)(n0 + rn) * DIN + k0 + ck] = f2bf(Ts[ck][rn]);
  }
}

// ---------- QKV GEMM; V written pi-permuted within each 64-tile ----------
__global__ __launch_bounds__(256) void k_qkv(const ushort_t* __restrict__ Xh,
                                             const ushort_t* __restrict__ WT,
                                             const float* __restrict__ bq,
                                             const float* __restrict__ bk,
                                             const float* __restrict__ bv,
                                             ushort_t* __restrict__ Qh,
                                             ushort_t* __restrict__ Kh,
                                             ushort_t* __restrict__ VT,
                                             int hl) {
  const int m0 = blockIdx.x * 128;
  const int n0 = blockIdx.y * 128;
  const int wsel = blockIdx.z;
  const ushort_t* Bt = WT + ((size_t)(wsel * 12 + hl)) * DD * DIN + (size_t)n0 * DIN;
  const float* bias = (wsel == 0) ? bq : (wsel == 1) ? bk : bv;

  __shared__ ushort_t As[128 * 64];
  __shared__ ushort_t Bs[128 * 64];
  const int tid = threadIdx.x;
  const int w = tid >> 6, lane = tid & 63;
  const int wr = w >> 1, wc = w & 1;
  const int lr = lane & 15, kg = lane >> 4;

  f32x4 acc[4][4];
  const f32x4 z4 = {0.f, 0.f, 0.f, 0.f};
#pragma unroll
  for (int a = 0; a < 4; ++a)
#pragma unroll
    for (int c = 0; c < 4; ++c) acc[a][c] = z4;

  for (int k0 = 0; k0 < DIN; k0 += 64) {
#pragma unroll
    for (int i = 0; i < 4; ++i) {
      const int idx = tid + i * 256;
      const int row = idx >> 3, ch = idx & 7;
      const int db = row * 128 + ((ch * 16) ^ ((row & 7) << 4));
      uint4 va = *(const uint4*)&Xh[(size_t)(m0 + row) * DIN + k0 + ch * 8];
      *(uint4*)((char*)As + db) = va;
      uint4 vb = *(const uint4*)&Bt[(size_t)row * DIN + k0 + ch * 8];
      *(uint4*)((char*)Bs + db) = vb;
    }
    __syncthreads();
#pragma unroll
    for (int kk = 0; kk < 2; ++kk) {
      short8 af[4], bfr[4];
      const int cb = kk * 64 + kg * 16;
#pragma unroll
      for (int mi = 0; mi < 4; ++mi) {
        const int row = wr * 64 + mi * 16 + lr;
        af[mi] = *(const short8*)((const char*)As + row * 128 + (cb ^ ((row & 7) << 4)));
      }
#pragma unroll
      for (int ni = 0; ni < 4; ++ni) {
        const int row = wc * 64 + ni * 16 + lr;
        bfr[ni] = *(const short8*)((const char*)Bs + row * 128 + (cb ^ ((row & 7) << 4)));
      }
#pragma unroll
      for (int mi = 0; mi < 4; ++mi)
#pragma unroll
        for (int ni = 0; ni < 4; ++ni)
          acc[mi][ni] = __builtin_amdgcn_mfma_f32_16x16x32_bf16(af[mi], bfr[ni], acc[mi][ni], 0, 0, 0);
    }
    __syncthreads();
  }

  if (wsel < 2) {
    ushort_t* C = (wsel == 0) ? Qh : Kh;
#pragma unroll
    for (int mi = 0; mi < 4; ++mi)
#pragma unroll
      for (int ni = 0; ni < 4; ++ni) {
        const int col = n0 + wc * 64 + ni * 16 + lr;
        const float bcol = bias[col];
        const int rbase = m0 + wr * 64 + mi * 16 + kg * 4;
#pragma unroll
        for (int r = 0; r < 4; ++r)
          C[(size_t)(rbase + r) * DD + col] = f2bf(acc[mi][ni][r] + bcol);
      }
  } else {
    // V: pi(j) = kg*16 + (g>>1)*8 + (g&1)*4 + e  (j = g*16 + kg*4 + e within tile)
    const int b2 = m0 >> 11;
    const int t0q = m0 & 2047;
#pragma unroll
    for (int mi = 0; mi < 4; ++mi)
#pragma unroll
      for (int ni = 0; ni < 4; ++ni) {
        const int col = n0 + wc * 64 + ni * 16 + lr;
        const float bcol = bias[col];
        const int dst = t0q + wr * 64 + kg * 16 + (mi >> 1) * 8 + (mi & 1) * 4;
        uint2 pk;
        pk.x = pack2(acc[mi][ni][0] + bcol, acc[mi][ni][1] + bcol);
        pk.y = pack2(acc[mi][ni][2] + bcol, acc[mi][ni][3] + bcol);
        *(uint2*)(VT + ((size_t)b2 * DD + col) * T2 + dst) = pk;
      }
  }
}

// ---------- flash: 2 waves x 16 q-rows, LDS double-buffer via global_load_lds ----------
// grid 256 x 128: b = (bx>>1)&3 (XCD pair), cc = bx>>3, hb = bx&1 (0=top,1=bottom).
__global__ __launch_bounds__(128, 1) void k_flash(const ushort_t* __restrict__ Qh,
                                                  const ushort_t* __restrict__ Kh,
                                                  const ushort_t* __restrict__ VT,
                                                  float* __restrict__ Cur,
                                                  ushort_t* __restrict__ Xh,
                                                  float* __restrict__ out,
                                                  const float* __restrict__ nw,
                                                  const float* __restrict__ nb,
                                                  int lastLayer, int h) {
  __shared__ char lds[131072];   // 2 x (K 32KB + V 32KB)
  const int tid = threadIdx.x;
  const int bx = blockIdx.x;
  const int b = (bx >> 1) & 3;
  const int cc = bx >> 3;
  const int hb = bx & 1;
  const int tcq = 31 - cc;               // heavy chunks first
  const int t0 = tcq * 32;
  const int ntop = (tcq >> 1) + 1;
  const int nt = ntop + hb;
  const int dtile = 16 + (tcq >> 1);
  const int off0 = (tcq & 1) * 32;

  const int w = tid >> 6, lane = tid & 63;
  const int kg = lane >> 4, lr = lane & 15;
  const int tloc = w * 16 + lr;
  const int t = t0 + tloc;
  const int r0lane = (hb ? T_ : 0) + t;
  const size_t bT2 = (size_t)b * T2;

  // Q B-fragments, loaded once
  short8 qf[8];
  {
    const ushort_t* qb = Qh + (bT2 + r0lane) * DD + kg * 8;
#pragma unroll
    for (int kk = 0; kk < 8; ++kk) qf[kk] = *(const short8*)(qb + kk * 32);
  }

  const f32x4 z4 = {0.f, 0.f, 0.f, 0.f};
  f32x4 acc_o[16];
#pragma unroll
  for (int db = 0; db < 16; ++db) acc_o[db] = z4;
  float m_run = -1e30f, l_run = 0.f;

  // stage one 64-row K tile + 256-d V tile into buffer at byte offset BO
#define STAGE(BO, TILE)                                                                  \
  {                                                                                      \
    const int _t = (TILE);                                                               \
    _Pragma("unroll") for (int s = 0; s < 16; ++s) {                                     \
      const int c = w * 16 + s;                                                          \
      {                                                                                  \
        const int j = (c << 1) | (lane >> 5);                                            \
        const int ch = lane & 31;                                                        \
        async_copy16((const char*)Kh + ((bT2 + _t * 64 + j) * DD) * 2 +                  \
                         ((ch * 16) ^ ((j & 7) << 4)),                                   \
                     lds + (BO) + c * 1024);                                             \
      }                                                                                  \
      {                                                                                  \
        const int d = (c << 3) | (lane >> 3);                                            \
        const int tc = lane & 7;                                                         \
        async_copy16((const char*)VT + (((size_t)b * DD + d) * T2 + _t * 64) * 2 +       \
                         ((tc * 16) ^ ((d & 7) << 4)),                                   \
                     lds + (BO) + 32768 + c * 1024);                                     \
      }                                                                                  \
    }                                                                                    \
  }

  int cur = 0;
  STAGE(0, 0);
  __syncthreads();

  for (int kt = 0; kt < nt; ++kt) {
    if (kt + 1 < nt) STAGE((cur ^ 1) * 65536, (kt + 1 < ntop) ? (kt + 1) : dtile);

    const int tile = (kt < ntop) ? kt : dtile;
    const bool isDiag = (kt >= ntop);
    const char* KsC = lds + cur * 65536;
    const char* VsC = KsC + 32768;

    // QK^T (swapped): S^T[j][q=lr]
    f32x4 sa[4];
#pragma unroll
    for (int jb = 0; jb < 4; ++jb) {
      sa[jb] = z4;
      const int rowj = jb * 16 + lr;
      const int base = rowj * 512;
      const int swj = (rowj & 7) << 4;
#pragma unroll
      for (int kk = 0; kk < 8; ++kk) {
        short8 kf = *(const short8*)(KsC + base + ((kk * 64 + kg * 16) ^ swj));
        sa[jb] = __builtin_amdgcn_mfma_f32_16x16x32_bf16(kf, qf[kk], sa[jb], 0, 0, 0);
      }
    }

    // mask + scale + online softmax (wave-local)
    float p[16];
    float tmax = -1e30f;
#pragma unroll
    for (int jb = 0; jb < 4; ++jb)
#pragma unroll
      for (int r = 0; r < 4; ++r) {
        const int jl = jb * 16 + kg * 4 + r;
        const bool valid = isDiag ? (jl == off0 + tloc) : ((tile * 64 + jl) < t);
        const float sv = valid ? sa[jb][r] * 0.0625f : -1e30f;
        p[jb * 4 + r] = sv;
        tmax = fmaxf(tmax, sv);
      }
    tmax = fmaxf(tmax, __shfl_xor(tmax, 16, 64));
    tmax = fmaxf(tmax, __shfl_xor(tmax, 32, 64));
    const float m_new = fmaxf(m_run, tmax);
    const float fac = __expf(m_run - m_new);
    float psum = 0.f;
#pragma unroll
    for (int e = 0; e < 16; ++e) {
      const float pe = (p[e] > -1e29f) ? __expf(p[e] - m_new) : 0.0f;
      p[e] = pe;
      psum += pe;
    }
    psum += __shfl_xor(psum, 16, 64);
    psum += __shfl_xor(psum, 32, 64);
    l_run = l_run * fac + psum;
    m_run = m_new;
#pragma unroll
    for (int db = 0; db < 16; ++db) acc_o[db] *= fac;

    // pack P into B-frags (lane-local, sigma k-slot order matching V pi-layout)
    union U8 { uint4 u; short8 s; };
    U8 pf0, pf1;
    pf0.u.x = cvtpk(p[0], p[1]);   pf0.u.y = cvtpk(p[2], p[3]);
    pf0.u.z = cvtpk(p[4], p[5]);   pf0.u.w = cvtpk(p[6], p[7]);
    pf1.u.x = cvtpk(p[8], p[9]);   pf1.u.y = cvtpk(p[10], p[11]);
    pf1.u.z = cvtpk(p[12], p[13]); pf1.u.w = cvtpk(p[14], p[15]);

    // PV: O^T += V^T * P^T; V frags are contiguous 16B in pi-layout
#pragma unroll
    for (int db = 0; db < 16; ++db) {
      const int d = db * 16 + lr;
      const char* vb = VsC + d * 128;
      const int swd = (d & 7) << 4;
      U8 vf0, vf1;
      vf0.u = *(const uint4*)(vb + ((kg * 32) ^ swd));
      vf1.u = *(const uint4*)(vb + ((kg * 32 + 16) ^ swd));
      acc_o[db] = __builtin_amdgcn_mfma_f32_16x16x32_bf16(vf0.s, pf0.s, acc_o[db], 0, 0, 0);
      acc_o[db] = __builtin_amdgcn_mfma_f32_16x16x32_bf16(vf1.s, pf1.s, acc_o[db], 0, 0, 0);
    }

    __syncthreads();   // next-tile staging complete; reads of cur done
    cur ^= 1;
  }

  // ---------- epilogue (wave-local) ----------
  const float oinv = 1.0f / l_run;   // t==0 (top): l==0 -> store skipped

  if (!hb) {
    if (t != 0) {
      ushort_t* xp = Xh + (bT2 + t) * DIN + kg * 4;
#pragma unroll
      for (int db = 0; db < 16; ++db) {
        us4v o;
#pragma unroll
        for (int r = 0; r < 4; ++r) o[r] = f2bf(acc_o[db][r] * oinv);
        *(us4v*)(xp + db * 16) = o;
      }
    }
  } else {
    float* cp = Cur + ((size_t)b * T_ + t) * DD + kg * 4;
    float s1 = 0.f, s2 = 0.f;
#pragma unroll
    for (int db = 0; db < 16; ++db) {
      f32x4 c4 = *(const f32x4*)(cp + db * 16);
#pragma unroll
      for (int r = 0; r < 4; ++r) {
        const float x = tanhf(acc_o[db][r] * oinv) + c4[r];
        acc_o[db][r] = x;
        s1 += x;
        s2 += x * x;
      }
    }
    s1 += __shfl_xor(s1, 16, 64); s1 += __shfl_xor(s1, 32, 64);
    s2 += __shfl_xor(s2, 16, 64); s2 += __shfl_xor(s2, 32, 64);
    const float mean = s1 * (1.0f / 256.0f);
    const float var = s2 * (1.0f / 256.0f) - mean * mean;
    const float rinv = rsqrtf(var + LNEPS);
    ushort_t* xp = Xh + (bT2 + T_ + t) * DIN + kg * 4;
    if (lastLayer) {
      float* op = out + ((size_t)b * T_ + t) * (DD * 4) + h * DD + kg * 4;
      const us4v zz = {0, 0, 0, 0};
      const f32x4 zf = {0.f, 0.f, 0.f, 0.f};
#pragma unroll
      for (int db = 0; db < 16; ++db) {
        f32x4 w4 = *(const f32x4*)&nw[db * 16 + kg * 4];
        f32x4 b4 = *(const f32x4*)&nb[db * 16 + kg * 4];
        f32x4 y;
#pragma unroll
        for (int r = 0; r < 4; ++r) y[r] = (acc_o[db][r] - mean) * rinv * w4[r] + b4[r];
        *(f32x4*)(op + db * 16) = y;
        *(f32x4*)(cp + db * 16) = zf;
        *(us4v*)(xp + db * 16) = zz;
      }
    } else {
#pragma unroll
      for (int db = 0; db < 16; ++db) {
        f32x4 w4 = *(const f32x4*)&nw[db * 16 + kg * 4];
        f32x4 b4 = *(const f32x4*)&nb[db * 16 + kg * 4];
        f32x4 y;
        us4v yh;
#pragma unroll
        for (int r = 0; r < 4; ++r) {
          y[r] = (acc_o[db][r] - mean) * rinv * w4[r] + b4[r];
          yh[r] = f2bf(y[r]);
        }
        *(f32x4*)(cp + db * 16) = y;
        *(us4v*)(xp + db * 16) = yh;
      }
    }
  }

  // ---------- row0 mean-V fold (4 lightest top blocks per batch) ----------
  if (!hb && tcq < 4) {
    __syncthreads();
    float* red = (float*)lds;
    const int col = tcq * 64 + (tid & 63);
    const int th = tid >> 6;
    const ushort_t* vp = VT + ((size_t)b * DD + col) * T2 + th * 1024;
    float s = 0.f;
#pragma unroll 4
    for (int j = 0; j < 1024; j += 8) {
      uint4 v = *(const uint4*)(vp + j);
      const uint_t vs[4] = {v.x, v.y, v.z, v.w};
#pragma unroll
      for (int q = 0; q < 4; ++q) {
        s += __uint_as_float(vs[q] << 16);
        s += __uint_as_float(vs[q] & 0xffff0000u);
      }
    }
    red[th * 64 + (tid & 63)] = s;
    __syncthreads();
    if (tid < 64)
      Xh[(size_t)b * T2 * DIN + tcq * 64 + tid] =
          f2bf((red[tid] + red[64 + tid]) * (1.0f / 2048.0f));
  }
#undef STAGE
}

extern "C" void kernel_launch(void* const* d_in, const int* in_sizes, int n_in,
                              void* d_out, int out_size, void* d_ws, size_t ws_size,
                              hipStream_t stream) {
  const float* ev = (const float*)d_in[0];
  const float* tm = (const float*)d_in[1];
  const float* Wt = (const float*)d_in[3];
  const float* bt = (const float*)d_in[4];
  const float* Wq = (const float*)d_in[5];
  const float* bq = (const float*)d_in[6];
  const float* Wk = (const float*)d_in[7];
  const float* bk = (const float*)d_in[8];
  const float* Wv = (const float*)d_in[9];
  const float* bv = (const float*)d_in[10];
  const float* nw = (const float*)d_in[11];
  const float* nb = (const float*)d_in[12];
  float* out = (float*)d_out;

  char* p = (char*)d_ws;
  ushort_t* Xh = (ushort_t*)p; p += (size_t)BB * T2 * DIN * 2;   // 8.39 MB
  ushort_t* Qh = (ushort_t*)p; p += (size_t)BB * T2 * DD * 2;    // 4.19 MB
  ushort_t* Kh = (ushort_t*)p; p += (size_t)BB * T2 * DD * 2;
  ushort_t* VT = (ushort_t*)p; p += (size_t)BB * T2 * DD * 2;
  float* Cur   = (float*)p;    p += (size_t)BB * T_ * DD * 4;    // 4.19 MB
  ushort_t* WT = (ushort_t*)p;                                   // 9.44 MB

  k_init<<<BB * T_, 256, 0, stream>>>(ev, tm, Wt, bt, Xh, Cur);
  k_transW<<<dim3(36, 32), 256, 0, stream>>>(Wq, Wk, Wv, WT);

  for (int h = 0; h < 4; ++h) {
    for (int l = 0; l < 3; ++l) {
      const int hl = h * 3 + l;
      const size_t boff = (size_t)hl * DD;
      k_qkv<<<dim3(64, 2, 3), 256, 0, stream>>>(Xh, WT, bq + boff, bk + boff, bv + boff,
                                                Qh, Kh, VT, hl);
      k_flash<<<256, 128, 0, stream>>>(Qh, Kh, VT, Cur, Xh, out, nw, nb,
                                       (l == 2) ? 1 : 0, h);
    }
  }
}